// Round 18
// baseline (425.956 us; speedup 1.0000x reference)
//
#include <hip/hip_runtime.h>
#include <hip/hip_bf16.h>
#include <cstdint>

typedef __bf16 bf16;
typedef bf16 bf16x4 __attribute__((ext_vector_type(4)));
typedef bf16 bf16x8 __attribute__((ext_vector_type(8)));
typedef float f32x4 __attribute__((ext_vector_type(4)));
typedef float f32x16 __attribute__((ext_vector_type(16)));
typedef uint32_t u32x4 __attribute__((ext_vector_type(4)));

#define NB 16
#define NL 1025
#define NDIM 1024
#define NHEADS 16
#define NCOND 256
#define NBH (NB*NHEADS)       // 256
#define NML (NB*NL)           // 16400
#define LP 1056               // padded kv length for v^T rows
#define NSLOT 17              // attn: balanced 32-row q-tile slots per bh
#define QSCALE (0.125f * 1.44269504088896340736f)  // sm_scale * log2(e)

__device__ __forceinline__ void gload16(const void* g, void* l) {
  __builtin_amdgcn_global_load_lds(
      (const __attribute__((address_space(1))) void*)(uintptr_t)g,
      (__attribute__((address_space(3))) void*)(uintptr_t)l,
      16, 0, 0);
}

__device__ __forceinline__ float fexp2(float x) {
  return __builtin_amdgcn_exp2f(x);   // raw v_exp_f32; exp2(-1e30) -> 0
}

__device__ __forceinline__ uint32_t cvtpk(float lo, float hi) {
  uint32_t r;
  asm("v_cvt_pk_bf16_f32 %0, %1, %2" : "=v"(r) : "v"(lo), "v"(hi));
  return r;   // lo -> bits [15:0], hi -> bits [31:16]
}

// lane[i] <-> lane[i+32] pairwise exchange on the VALU pipe (T12).
__device__ __forceinline__ void plswap(uint32_t& a, uint32_t& b) {
  asm volatile("v_permlane32_swap_b32 %0, %1" : "+v"(a), "+v"(b));
}

__device__ __forceinline__ f32x16 zero16() {
  f32x16 z;
#pragma unroll
  for (int i = 0; i < 16; ++i) z[i] = 0.f;
  return z;
}

// ---------------- merged prep: cast wqkv, cast wout, cond scale ----------------
// blocks [0,3072): wqkv cast; [3072,4096): wout cast; [4096,4112): scale rows.
__global__ __launch_bounds__(256) void k_prep(const float* __restrict__ wqkv,
                                              const float* __restrict__ wout,
                                              const float* __restrict__ cond,
                                              const float* __restrict__ wn,
                                              bf16* __restrict__ wq,
                                              bf16* __restrict__ wo,
                                              float* __restrict__ scl) {
  __shared__ float cs[NCOND];
  const int bid = blockIdx.x, t = threadIdx.x;
  if (bid < 4096) {
    const float* src = (bid < 3072) ? wqkv : wout;
    bf16* dst = (bid < 3072) ? wq : wo;
    const int lb = (bid < 3072) ? bid : bid - 3072;
    const int i = (lb * 256 + t) * 4;
    float4 v = *(const float4*)(src + i);
    bf16x4 o;
    o[0] = (bf16)v.x; o[1] = (bf16)v.y; o[2] = (bf16)v.z; o[3] = (bf16)v.w;
    *(bf16x4*)(dst + i) = o;
  } else {
    const int b = bid - 4096;
    cs[t] = cond[b * NCOND + t];
    __syncthreads();
#pragma unroll
    for (int dd = 0; dd < 4; ++dd) {
      const int d = t * 4 + dd;
      const float4* w = (const float4*)(wn + (size_t)d * NCOND);
      float acc = 1.0f;
      for (int c4 = 0; c4 < NCOND / 4; ++c4) {
        float4 wv = w[c4];
        acc += wv.x * cs[c4*4] + wv.y * cs[c4*4+1] + wv.z * cs[c4*4+2] + wv.w * cs[c4*4+3];
      }
      scl[b * NDIM + d] = acc;
    }
  }
}

// ---------------- RMSNorm * scale -> xn (bf16), wave-per-row ----------------
// 4 rows per block (one wave each); per-wave shuffle reduce only (no LDS, no
// barrier). 16400 = 4 * 4100, no tail. Lane covers cols 4*lane + 256*i.
__global__ __launch_bounds__(256) void k_rmsnorm(const float* __restrict__ x,
                                                 const float* __restrict__ scl,
                                                 bf16* __restrict__ xn) {
  const int wave = threadIdx.x >> 6, lane = threadIdx.x & 63;
  const int row = blockIdx.x * 4 + wave;
  const int b = row / NL;
  const float* xr = x + (size_t)row * NDIM;
  float4 v[4];
  float ss = 0.f;
#pragma unroll
  for (int i = 0; i < 4; ++i) {
    v[i] = *(const float4*)(xr + i * 256 + lane * 4);
    ss += v[i].x * v[i].x + v[i].y * v[i].y + v[i].z * v[i].z + v[i].w * v[i].w;
  }
#pragma unroll
  for (int o = 1; o < 64; o <<= 1) ss += __shfl_xor(ss, o);
  const float rn = rsqrtf(ss * (1.0f / NDIM) + 1e-6f);
  const float* sb = scl + (size_t)b * NDIM;
  bf16* xo = xn + (size_t)row * NDIM;
#pragma unroll
  for (int i = 0; i < 4; ++i) {
    const float4 sc = *(const float4*)(sb + i * 256 + lane * 4);
    bf16x4 o4;
    o4[0] = (bf16)(v[i].x * sc.x * rn);
    o4[1] = (bf16)(v[i].y * sc.y * rn);
    o4[2] = (bf16)(v[i].z * sc.z * rn);
    o4[3] = (bf16)(v[i].w * sc.w * rn);
    *(bf16x4*)(xo + i * 256 + lane * 4) = o4;
  }
}

// ---------------- GEMM: C[m,n] = sum_k A[m,k]*B[n,k]  (both row-major, B^T) ----
// R12-proven config: 128x128 tile, 4 waves, BK=64, 2-buffer counted-vmcnt
// pipeline { stage(t+1); vmcnt(8); barrier; ds_read+MFMA (setprio); barrier },
// XOR-granule swizzle (0 bank conflicts), bijective XCD-grouped 1D grid.
// EPI=1: store f32 + skip add. EPI=2: fused RoPE/layout epilogue.
template <int EPI>
__global__ __launch_bounds__(256) void k_gemm(const bf16* __restrict__ A,
                                              const bf16* __restrict__ Bm,
                                              int M, int N, int K,
                                              float* __restrict__ Cf,
                                              const float* __restrict__ skip,
                                              bf16* __restrict__ qro,
                                              bf16* __restrict__ kro,
                                              bf16* __restrict__ vto,
                                              const float* __restrict__ cosT,
                                              const float* __restrict__ sinT) {
  __shared__ bf16 Als[2][128 * 64];
  __shared__ bf16 Bls[2][128 * 64];
  const int t = threadIdx.x;
  const int wave = t >> 6, lane = t & 63;
  const int g = lane >> 4, c = lane & 15;
  const int wm = wave >> 1, wn_ = wave & 1;

  const int nxb = N >> 7;
  const int nwg = gridDim.x;
  const int cpx = nwg >> 3;
  const int bid = blockIdx.x;
  const int swz = (nwg & 7) ? bid : (bid & 7) * cpx + (bid >> 3);  // XCD-grouped
  const int m0 = (swz / nxb) * 128, n0 = (swz % nxb) * 128;
  const int NT = K >> 6;

  const int srow = lane >> 3;                 // row within 8-row segment
  const int scol = ((lane & 7) ^ srow) * 8;   // pre-swizzled source granule

  f32x4 acc[4][4];
#pragma unroll
  for (int i = 0; i < 4; ++i)
#pragma unroll
    for (int j = 0; j < 4; ++j) acc[i][j] = f32x4{0.f, 0.f, 0.f, 0.f};

  auto stage = [&](int kt, int q) {
    const int k0 = kt << 6;
#pragma unroll
    for (int i = 0; i < 4; ++i) {
      const int seg = wave * 4 + i;
      int arow = m0 + seg * 8 + srow;
      if (arow >= M) arow = M - 1;
      gload16(A + (size_t)arow * K + k0 + scol, &Als[q][seg * 512]);
      const int brow = n0 + seg * 8 + srow;   // N % 128 == 0, no clamp
      gload16(Bm + (size_t)brow * K + k0 + scol, &Bls[q][seg * 512]);
    }
  };

  stage(0, 0);                                 // 8 loads in flight
  for (int kt = 0; kt < NT; ++kt) {
    const int cur = kt & 1;
    if (kt + 1 < NT) {
      stage(kt + 1, cur ^ 1);                  // 16 in flight
      asm volatile("s_waitcnt vmcnt(8)" ::: "memory");  // stage(kt) retired
    } else {
      asm volatile("s_waitcnt vmcnt(0)" ::: "memory");  // tail drain
    }
    __builtin_amdgcn_s_barrier();              // all waves' stage(kt) visible
    asm volatile("" ::: "memory");
#pragma unroll
    for (int kc = 0; kc < 2; ++kc) {
      bf16x8 af[4], bfr[4];
#pragma unroll
      for (int mi = 0; mi < 4; ++mi) {
        const int r = wm * 64 + mi * 16 + c;
        const int gg = ((kc * 4 + g) ^ (c & 7)) * 8;
        af[mi] = *(const bf16x8*)&Als[cur][r * 64 + gg];
      }
#pragma unroll
      for (int ni = 0; ni < 4; ++ni) {
        const int r = wn_ * 64 + ni * 16 + c;
        const int gg = ((kc * 4 + g) ^ (c & 7)) * 8;
        bfr[ni] = *(const bf16x8*)&Bls[cur][r * 64 + gg];
      }
      __builtin_amdgcn_s_setprio(1);
#pragma unroll
      for (int mi = 0; mi < 4; ++mi)
#pragma unroll
        for (int ni = 0; ni < 4; ++ni)
          acc[mi][ni] = __builtin_amdgcn_mfma_f32_16x16x32_bf16(af[mi], bfr[ni], acc[mi][ni], 0, 0, 0);
      __builtin_amdgcn_s_setprio(0);
    }
    asm volatile("" ::: "memory");
    __builtin_amdgcn_s_barrier();              // reads of buf done before overwrite
  }

  if (EPI == 1) {
#pragma unroll
    for (int mi = 0; mi < 4; ++mi) {
      const int rb = m0 + wm * 64 + mi * 16 + g * 4;
#pragma unroll
      for (int ni = 0; ni < 4; ++ni) {
        const int col = n0 + wn_ * 64 + ni * 16 + c;
#pragma unroll
        for (int j = 0; j < 4; ++j) {
          const int row = rb + j;
          if (row < M) {
            const size_t idx = (size_t)row * N + col;
            Cf[idx] = acc[mi][ni][j] + skip[idx];
          }
        }
      }
    }
  } else {
    // EPI==2: fused RoPE + layout epilogue
    const int ncol0 = n0 + wn_ * 64;
    const int type = ncol0 >> 10;              // 0=q, 1=k, 2=v
    const int hd = (ncol0 & 1023) >> 6;        // head
    if (type == 2) {
      // V: vt[bh][d][LP] with d = ni*16+c; 4 consecutive l per (mi) -> bf16x4
#pragma unroll
      for (int mi = 0; mi < 4; ++mi) {
        const int rb = m0 + wm * 64 + mi * 16 + g * 4;
        const int b0 = rb / NL, b3 = (rb + 3) / NL;
        if (rb + 3 < M && b0 == b3) {
          const int l0_ = rb - b0 * NL;
          const size_t bhb = (size_t)(b0 * NHEADS + hd) * 64;
#pragma unroll
          for (int ni = 0; ni < 4; ++ni) {
            const int d = ni * 16 + c;
            bf16x4 v4;
#pragma unroll
            for (int j = 0; j < 4; ++j) v4[j] = (bf16)acc[mi][ni][j];
            *(bf16x4*)(vto + (bhb + d) * LP + l0_) = v4;
          }
        } else {
#pragma unroll
          for (int j = 0; j < 4; ++j) {
            const int row = rb + j;
            if (row < M) {
              const int b_ = row / NL, l = row - b_ * NL;
              const size_t bhb = (size_t)(b_ * NHEADS + hd) * 64;
#pragma unroll
              for (int ni = 0; ni < 4; ++ni)
                vto[(bhb + ni * 16 + c) * LP + l] = (bf16)acc[mi][ni][j];
            }
          }
        }
      }
    } else {
      bf16* dst = (type == 0) ? qro : kro;
      const float qs = (type == 0) ? QSCALE : 1.0f;
#pragma unroll
      for (int mi = 0; mi < 4; ++mi) {
        const int rb = m0 + wm * 64 + mi * 16 + g * 4;
#pragma unroll
        for (int j = 0; j < 4; ++j) {
          const int row = rb + j;
          if (row < M) {
            const int b_ = row / NL, l = row - b_ * NL;
            const float cf = cosT[l * 16 + c], sf = sinT[l * 16 + c];
            const float a0 = acc[mi][0][j], a1 = acc[mi][1][j];
            const float r0 = (a0 * cf - a1 * sf) * qs;
            const float r1 = (a1 * cf + a0 * sf) * qs;
            const float r2 = acc[mi][2][j] * qs;
            const float r3 = acc[mi][3][j] * qs;
            const size_t bse = ((size_t)(b_ * NHEADS + hd) * NL + l) * 64;
            dst[bse + c]      = (bf16)r0;
            dst[bse + 16 + c] = (bf16)r1;
            dst[bse + 32 + c] = (bf16)r2;
            dst[bse + 48 + c] = (bf16)r3;
          }
        }
      }
    }
  }
}

// ---------------- causal flash attention: dual-tile interleaved, no LDS ----
// One wave per slot; slot s<16 runs tiles {s, 31-s} interleaved in one kv loop;
// slot 16 runs tile 32 alone. P-repack lane exchange via v_permlane32_swap
// (VALU pipe): (word0,word2)=swap(w0,w2), (word1,word3)=swap(w1,w3).
// No setprio (measured regression R9/R15). PROVEN R16 @421.6us.
__global__ __launch_bounds__(64) void k_attn(const bf16* __restrict__ qr,
                                             const bf16* __restrict__ kr,
                                             const bf16* __restrict__ vt,
                                             bf16* __restrict__ oa) {
  const int bid = blockIdx.x;                    // grid = 4352 = 8 * 544
  const int lbid = (bid & 7) * (NBH * NSLOT / 8) + (bid >> 3);  // XCD-grouped
  const int slot = lbid % NSLOT, bh = lbid / NSLOT;
  const int b = bh >> 4, h = bh & 15;
  const int lane = threadIdx.x;
  const int ql = lane & 31;                      // q-col / kv-row / d-col index
  const int hh = lane >> 5;                      // half (k-chunk selector)
  const bf16* qb = qr + (size_t)bh * NL * 64;
  const bf16* kb = kr + (size_t)bh * NL * 64;
  const bf16* vb = vt + (size_t)bh * 64 * LP;

  const int tA = (slot < 16) ? slot : -1;
  const int tB = (slot < 16) ? 31 - slot : 32;
  const bool hasA = (tA >= 0);

  const int q0A = tA * 32, q0B = tB * 32;
  const int qabsA = q0A + ql, qabsB = q0B + ql;

  bf16x8 bQA[4], bQB[4];
  {
    const int qrB = (q0B + ql < NL) ? q0B + ql : NL - 1;
#pragma unroll
    for (int kc = 0; kc < 4; ++kc)
      bQB[kc] = *(const bf16x8*)(qb + (size_t)qrB * 64 + kc * 16 + hh * 8);
    const int qrA = hasA ? q0A + ql : 0;
#pragma unroll
    for (int kc = 0; kc < 4; ++kc)
      bQA[kc] = *(const bf16x8*)(qb + (size_t)qrA * 64 + kc * 16 + hh * 8);
  }

  f32x16 odA0 = zero16(), odA1 = zero16(), odB0 = zero16(), odB1 = zero16();
  float lsA = 0.f, lsB = 0.f;

  const int ntA = hasA ? ((q0A + 31) / 64 + 1) : 0;
  const int qmaxB = (q0B + 31 < NL - 1) ? q0B + 31 : NL - 1;
  const int ntB = qmaxB / 64 + 1;               // ntA <= ntB always

  bf16x8 aK[2][4];
  auto loadK = [&](int kv0) {
#pragma unroll
    for (int blk = 0; blk < 2; ++blk) {
      int r = kv0 + blk * 32 + ql; if (r >= NL) r = NL - 1;
      const bf16* kp = kb + (size_t)r * 64 + hh * 8;
#pragma unroll
      for (int kc = 0; kc < 4; ++kc)
        aK[blk][kc] = *(const bf16x8*)(kp + kc * 16);
    }
  };
  loadK(0);

  auto smrepack = [&](const f32x16& s0, const f32x16& s1, int kv0, int q0,
                      int qabs, float& ls, bf16x8 (&pa)[4]) {
    const bool needmask = (kv0 + 63 > q0);
#pragma unroll
    for (int blk = 0; blk < 2; ++blk) {
      const f32x16& s = blk ? s1 : s0;
      float p[16];
#pragma unroll
      for (int r = 0; r < 16; ++r) {
        float v = s[r];
        if (needmask) {
          const int kvabs = kv0 + blk * 32 + (r & 3) + 8 * (r >> 2) + 4 * hh;
          if (kvabs > qabs) v = -1e30f;
        }
        p[r] = fexp2(v);
      }
      ls += (((p[0]+p[1])+(p[2]+p[3])) + ((p[4]+p[5])+(p[6]+p[7])))
          + (((p[8]+p[9])+(p[10]+p[11])) + ((p[12]+p[13])+(p[14]+p[15])));
      uint32_t w[8];
#pragma unroll
      for (int a = 0; a < 8; ++a) w[a] = cvtpk(p[2*a], p[2*a+1]);
      // VALU-pipe exchange (replaces 4 DS shuffles):
      uint32_t a0 = w[0], b0 = w[2]; plswap(a0, b0);
      uint32_t a1 = w[1], b1 = w[3]; plswap(a1, b1);
      uint32_t a2 = w[4], b2 = w[6]; plswap(a2, b2);
      uint32_t a3 = w[5], b3 = w[7]; plswap(a3, b3);
      u32x4 w0_, w1_;
      w0_[0] = a0; w0_[1] = a1; w0_[2] = b0; w0_[3] = b1;
      w1_[0] = a2; w1_[1] = a3; w1_[2] = b2; w1_[3] = b3;
      pa[2*blk]     = __builtin_bit_cast(bf16x8, w0_);
      pa[2*blk + 1] = __builtin_bit_cast(bf16x8, w1_);
    }
  };

  for (int tk = 0; tk < ntB; ++tk) {
    const int kv0 = tk * 64;
    const bool actA = hasA && (tk < ntA);

    bf16x8 vf[2][4];
#pragma unroll
    for (int dblk = 0; dblk < 2; ++dblk) {
      const bf16* vp = vb + (size_t)(dblk * 32 + ql) * LP;
#pragma unroll
      for (int kc = 0; kc < 4; ++kc) {
        int col = kv0 + kc * 16 + hh * 8;
        if (col > LP - 8) col = LP - 8;       // final-tile clamp (P=0 there)
        vf[dblk][kc] = *(const bf16x8*)(vp + col);
      }
    }

    bf16x8 paA[4];
    if (actA) {
      f32x16 s0 = zero16(), s1 = zero16();
#pragma unroll
      for (int kc = 0; kc < 4; ++kc)
        s0 = __builtin_amdgcn_mfma_f32_32x32x16_bf16(aK[0][kc], bQA[kc], s0, 0, 0, 0);
#pragma unroll
      for (int kc = 0; kc < 4; ++kc)
        s1 = __builtin_amdgcn_mfma_f32_32x32x16_bf16(aK[1][kc], bQA[kc], s1, 0, 0, 0);
      smrepack(s0, s1, kv0, q0A, qabsA, lsA, paA);
    }

    f32x16 sB0 = zero16(), sB1 = zero16();
#pragma unroll
    for (int kc = 0; kc < 4; ++kc)
      sB0 = __builtin_amdgcn_mfma_f32_32x32x16_bf16(aK[0][kc], bQB[kc], sB0, 0, 0, 0);
#pragma unroll
    for (int kc = 0; kc < 4; ++kc)
      sB1 = __builtin_amdgcn_mfma_f32_32x32x16_bf16(aK[1][kc], bQB[kc], sB1, 0, 0, 0);

    if (tk + 1 < ntB) loadK(kv0 + 64);

    if (actA) {
#pragma unroll
      for (int kc = 0; kc < 4; ++kc) {
        odA0 = __builtin_amdgcn_mfma_f32_32x32x16_bf16(paA[kc], vf[0][kc], odA0, 0, 0, 0);
        odA1 = __builtin_amdgcn_mfma_f32_32x32x16_bf16(paA[kc], vf[1][kc], odA1, 0, 0, 0);
      }
    }

    bf16x8 paB[4];
    smrepack(sB0, sB1, kv0, q0B, qabsB, lsB, paB);

#pragma unroll
    for (int kc = 0; kc < 4; ++kc) {
      odB0 = __builtin_amdgcn_mfma_f32_32x32x16_bf16(paB[kc], vf[0][kc], odB0, 0, 0, 0);
      odB1 = __builtin_amdgcn_mfma_f32_32x32x16_bf16(paB[kc], vf[1][kc], odB1, 0, 0, 0);
    }
  }

  auto fin = [&](int q0, float ls, const f32x16& od0, const f32x16& od1) {
    const float tot = ls + __shfl_xor(ls, 32);
    const float invOwn = 1.0f / tot;
#pragma unroll
    for (int r = 0; r < 16; ++r) {
      const int qrl = (r & 3) + 8 * (r >> 2) + 4 * hh;   // local q row of reg r
      const float inv = __shfl(invOwn, qrl);
      const int row = q0 + qrl;
      if (row < NL) {
        const size_t ob = (size_t)(b * NL + row) * NDIM + h * 64;
        oa[ob + ql]      = (bf16)(od0[r] * inv);
        oa[ob + 32 + ql] = (bf16)(od1[r] * inv);
      }
    }
  };
  if (hasA) fin(q0A, lsA, odA0, odA1);
  fin(q0B, lsB, odB0, odB1);
}

extern "C" void kernel_launch(void* const* d_in, const int* in_sizes, int n_in,
                              void* d_out, int out_size, void* d_ws, size_t ws_size,
                              hipStream_t stream) {
  const float* x     = (const float*)d_in[0];
  const float* cond  = (const float*)d_in[1];
  const float* wnorm = (const float*)d_in[2];
  const float* wqkv  = (const float*)d_in[3];
  const float* wout  = (const float*)d_in[4];
  const float* cosT  = (const float*)d_in[5];
  const float* sinT  = (const float*)d_in[6];
  float* out = (float*)d_out;
  char* ws = (char*)d_ws;

  float* s_scl = (float*)(ws);                    //    65,536 B
  bf16*  s_wq  = (bf16*)(ws + 65536);             // 6,291,456 B
  bf16*  s_wo  = (bf16*)(ws + 6356992);           // 2,097,152 B
  bf16*  s_xn  = (bf16*)(ws + 8454144);           // 33,587,200 B (reused as attn out)
  bf16*  s_qr  = (bf16*)(ws + 142802944);         // 33,587,200 B
  bf16*  s_kr  = (bf16*)(ws + 176390144);         // 33,587,200 B
  bf16*  s_vt  = (bf16*)(ws + 209977344);         // 34,603,008 B -> end 244,580,352 B

  k_prep<<<4112, 256, 0, stream>>>(wqkv, wout, cond, wnorm, s_wq, s_wo, s_scl);
  k_rmsnorm<<<4100, 256, 0, stream>>>(x, s_scl, s_xn);
  k_gemm<2><<<3096, 256, 0, stream>>>(s_xn, s_wq, NML, 3 * NDIM, NDIM,
                                      nullptr, nullptr, s_qr, s_kr, s_vt,
                                      cosT, sinT);
  k_attn<<<NBH * NSLOT, 64, 0, stream>>>(s_qr, s_kr, s_vt, s_xn);
  k_gemm<1><<<1032, 256, 0, stream>>>(s_xn, s_wo, NML, NDIM, NDIM,
                                      out, x, nullptr, nullptr, nullptr,
                                      nullptr, nullptr);
}

// Round 19
// 423.668 us; speedup vs baseline: 1.0054x; 1.0054x over previous
//
#include <hip/hip_runtime.h>
#include <hip/hip_bf16.h>
#include <cstdint>

typedef __bf16 bf16;
typedef bf16 bf16x4 __attribute__((ext_vector_type(4)));
typedef bf16 bf16x8 __attribute__((ext_vector_type(8)));
typedef float f32x4 __attribute__((ext_vector_type(4)));
typedef float f32x16 __attribute__((ext_vector_type(16)));
typedef uint32_t u32x4 __attribute__((ext_vector_type(4)));

#define NB 16
#define NL 1025
#define NDIM 1024
#define NHEADS 16
#define NCOND 256
#define NBH (NB*NHEADS)       // 256
#define NML (NB*NL)           // 16400
#define LP 1056               // padded kv length for v^T rows
#define NSLOT 17              // attn: balanced 32-row q-tile slots per bh
#define QSCALE (0.125f * 1.44269504088896340736f)  // sm_scale * log2(e)

__device__ __forceinline__ void gload16(const void* g, void* l) {
  __builtin_amdgcn_global_load_lds(
      (const __attribute__((address_space(1))) void*)(uintptr_t)g,
      (__attribute__((address_space(3))) void*)(uintptr_t)l,
      16, 0, 0);
}

__device__ __forceinline__ float fexp2(float x) {
  return __builtin_amdgcn_exp2f(x);   // raw v_exp_f32; exp2(-1e30) -> 0
}

__device__ __forceinline__ uint32_t cvtpk(float lo, float hi) {
  uint32_t r;
  asm("v_cvt_pk_bf16_f32 %0, %1, %2" : "=v"(r) : "v"(lo), "v"(hi));
  return r;   // lo -> bits [15:0], hi -> bits [31:16]
}

// lane[i] <-> lane[i+32] pairwise exchange on the VALU pipe (T12).
__device__ __forceinline__ void plswap(uint32_t& a, uint32_t& b) {
  asm volatile("v_permlane32_swap_b32 %0, %1" : "+v"(a), "+v"(b));
}

__device__ __forceinline__ f32x16 zero16() {
  f32x16 z;
#pragma unroll
  for (int i = 0; i < 16; ++i) z[i] = 0.f;
  return z;
}

// ---------------- merged prep: cast wqkv, cast wout, cond scale ----------------
// blocks [0,3072): wqkv cast; [3072,4096): wout cast; [4096,4112): scale rows.
__global__ __launch_bounds__(256) void k_prep(const float* __restrict__ wqkv,
                                              const float* __restrict__ wout,
                                              const float* __restrict__ cond,
                                              const float* __restrict__ wn,
                                              bf16* __restrict__ wq,
                                              bf16* __restrict__ wo,
                                              float* __restrict__ scl) {
  __shared__ float cs[NCOND];
  const int bid = blockIdx.x, t = threadIdx.x;
  if (bid < 4096) {
    const float* src = (bid < 3072) ? wqkv : wout;
    bf16* dst = (bid < 3072) ? wq : wo;
    const int lb = (bid < 3072) ? bid : bid - 3072;
    const int i = (lb * 256 + t) * 4;
    float4 v = *(const float4*)(src + i);
    bf16x4 o;
    o[0] = (bf16)v.x; o[1] = (bf16)v.y; o[2] = (bf16)v.z; o[3] = (bf16)v.w;
    *(bf16x4*)(dst + i) = o;
  } else {
    const int b = bid - 4096;
    cs[t] = cond[b * NCOND + t];
    __syncthreads();
#pragma unroll
    for (int dd = 0; dd < 4; ++dd) {
      const int d = t * 4 + dd;
      const float4* w = (const float4*)(wn + (size_t)d * NCOND);
      float acc = 1.0f;
      for (int c4 = 0; c4 < NCOND / 4; ++c4) {
        float4 wv = w[c4];
        acc += wv.x * cs[c4*4] + wv.y * cs[c4*4+1] + wv.z * cs[c4*4+2] + wv.w * cs[c4*4+3];
      }
      scl[b * NDIM + d] = acc;
    }
  }
}

// ---------------- RMSNorm * scale -> xn (bf16) ----------------
// R16-proven block-per-row version.
__global__ __launch_bounds__(256) void k_rmsnorm(const float* __restrict__ x,
                                                 const float* __restrict__ scl,
                                                 bf16* __restrict__ xn) {
  const int row = blockIdx.x, t = threadIdx.x;
  const int b = row / NL;
  const float* xr = x + (size_t)row * NDIM;
  float4 v = *(const float4*)(xr + t * 4);
  float ss = v.x*v.x + v.y*v.y + v.z*v.z + v.w*v.w;
#pragma unroll
  for (int o = 1; o < 64; o <<= 1) ss += __shfl_xor(ss, o);
  __shared__ float red[4];
  if ((t & 63) == 0) red[t >> 6] = ss;
  __syncthreads();
  const float tot = red[0] + red[1] + red[2] + red[3];
  const float rn = rsqrtf(tot * (1.0f / NDIM) + 1e-6f);
  const float4 sc = *(const float4*)(scl + b * NDIM + t * 4);
  bf16x4 o4;
  o4[0] = (bf16)(v.x * sc.x * rn);
  o4[1] = (bf16)(v.y * sc.y * rn);
  o4[2] = (bf16)(v.z * sc.z * rn);
  o4[3] = (bf16)(v.w * sc.w * rn);
  *(bf16x4*)(xn + (size_t)row * NDIM + t * 4) = o4;
}

// ---------------- GEMM: C[m,n] = sum_k A[m,k]*B[n,k]  (both row-major, B^T) ----
// R12-proven config: 128x128 tile, 4 waves, BK=64, 2-buffer counted-vmcnt
// pipeline { stage(t+1); vmcnt(8); barrier; ds_read+MFMA (setprio); barrier },
// XOR-granule swizzle (0 bank conflicts), bijective XCD-grouped 1D grid.
// EPI=1: store f32 + skip add. EPI=2: fused RoPE/layout epilogue.
template <int EPI>
__global__ __launch_bounds__(256) void k_gemm(const bf16* __restrict__ A,
                                              const bf16* __restrict__ Bm,
                                              int M, int N, int K,
                                              float* __restrict__ Cf,
                                              const float* __restrict__ skip,
                                              bf16* __restrict__ qro,
                                              bf16* __restrict__ kro,
                                              bf16* __restrict__ vto,
                                              const float* __restrict__ cosT,
                                              const float* __restrict__ sinT) {
  __shared__ bf16 Als[2][128 * 64];
  __shared__ bf16 Bls[2][128 * 64];
  const int t = threadIdx.x;
  const int wave = t >> 6, lane = t & 63;
  const int g = lane >> 4, c = lane & 15;
  const int wm = wave >> 1, wn_ = wave & 1;

  const int nxb = N >> 7;
  const int nwg = gridDim.x;
  const int cpx = nwg >> 3;
  const int bid = blockIdx.x;
  const int swz = (nwg & 7) ? bid : (bid & 7) * cpx + (bid >> 3);  // XCD-grouped
  const int m0 = (swz / nxb) * 128, n0 = (swz % nxb) * 128;
  const int NT = K >> 6;

  const int srow = lane >> 3;                 // row within 8-row segment
  const int scol = ((lane & 7) ^ srow) * 8;   // pre-swizzled source granule

  f32x4 acc[4][4];
#pragma unroll
  for (int i = 0; i < 4; ++i)
#pragma unroll
    for (int j = 0; j < 4; ++j) acc[i][j] = f32x4{0.f, 0.f, 0.f, 0.f};

  auto stage = [&](int kt, int q) {
    const int k0 = kt << 6;
#pragma unroll
    for (int i = 0; i < 4; ++i) {
      const int seg = wave * 4 + i;
      int arow = m0 + seg * 8 + srow;
      if (arow >= M) arow = M - 1;
      gload16(A + (size_t)arow * K + k0 + scol, &Als[q][seg * 512]);
      const int brow = n0 + seg * 8 + srow;   // N % 128 == 0, no clamp
      gload16(Bm + (size_t)brow * K + k0 + scol, &Bls[q][seg * 512]);
    }
  };

  stage(0, 0);                                 // 8 loads in flight
  for (int kt = 0; kt < NT; ++kt) {
    const int cur = kt & 1;
    if (kt + 1 < NT) {
      stage(kt + 1, cur ^ 1);                  // 16 in flight
      asm volatile("s_waitcnt vmcnt(8)" ::: "memory");  // stage(kt) retired
    } else {
      asm volatile("s_waitcnt vmcnt(0)" ::: "memory");  // tail drain
    }
    __builtin_amdgcn_s_barrier();              // all waves' stage(kt) visible
    asm volatile("" ::: "memory");
#pragma unroll
    for (int kc = 0; kc < 2; ++kc) {
      bf16x8 af[4], bfr[4];
#pragma unroll
      for (int mi = 0; mi < 4; ++mi) {
        const int r = wm * 64 + mi * 16 + c;
        const int gg = ((kc * 4 + g) ^ (c & 7)) * 8;
        af[mi] = *(const bf16x8*)&Als[cur][r * 64 + gg];
      }
#pragma unroll
      for (int ni = 0; ni < 4; ++ni) {
        const int r = wn_ * 64 + ni * 16 + c;
        const int gg = ((kc * 4 + g) ^ (c & 7)) * 8;
        bfr[ni] = *(const bf16x8*)&Bls[cur][r * 64 + gg];
      }
      __builtin_amdgcn_s_setprio(1);
#pragma unroll
      for (int mi = 0; mi < 4; ++mi)
#pragma unroll
        for (int ni = 0; ni < 4; ++ni)
          acc[mi][ni] = __builtin_amdgcn_mfma_f32_16x16x32_bf16(af[mi], bfr[ni], acc[mi][ni], 0, 0, 0);
      __builtin_amdgcn_s_setprio(0);
    }
    asm volatile("" ::: "memory");
    __builtin_amdgcn_s_barrier();              // reads of buf done before overwrite
  }

  if (EPI == 1) {
#pragma unroll
    for (int mi = 0; mi < 4; ++mi) {
      const int rb = m0 + wm * 64 + mi * 16 + g * 4;
#pragma unroll
      for (int ni = 0; ni < 4; ++ni) {
        const int col = n0 + wn_ * 64 + ni * 16 + c;
#pragma unroll
        for (int j = 0; j < 4; ++j) {
          const int row = rb + j;
          if (row < M) {
            const size_t idx = (size_t)row * N + col;
            Cf[idx] = acc[mi][ni][j] + skip[idx];
          }
        }
      }
    }
  } else {
    // EPI==2: fused RoPE + layout epilogue
    const int ncol0 = n0 + wn_ * 64;
    const int type = ncol0 >> 10;              // 0=q, 1=k, 2=v
    const int hd = (ncol0 & 1023) >> 6;        // head
    if (type == 2) {
      // V: vt[bh][d][LP] with d = ni*16+c; 4 consecutive l per (mi) -> bf16x4
#pragma unroll
      for (int mi = 0; mi < 4; ++mi) {
        const int rb = m0 + wm * 64 + mi * 16 + g * 4;
        const int b0 = rb / NL, b3 = (rb + 3) / NL;
        if (rb + 3 < M && b0 == b3) {
          const int l0_ = rb - b0 * NL;
          const size_t bhb = (size_t)(b0 * NHEADS + hd) * 64;
#pragma unroll
          for (int ni = 0; ni < 4; ++ni) {
            const int d = ni * 16 + c;
            bf16x4 v4;
#pragma unroll
            for (int j = 0; j < 4; ++j) v4[j] = (bf16)acc[mi][ni][j];
            *(bf16x4*)(vto + (bhb + d) * LP + l0_) = v4;
          }
        } else {
#pragma unroll
          for (int j = 0; j < 4; ++j) {
            const int row = rb + j;
            if (row < M) {
              const int b_ = row / NL, l = row - b_ * NL;
              const size_t bhb = (size_t)(b_ * NHEADS + hd) * 64;
#pragma unroll
              for (int ni = 0; ni < 4; ++ni)
                vto[(bhb + ni * 16 + c) * LP + l] = (bf16)acc[mi][ni][j];
            }
          }
        }
      }
    } else {
      bf16* dst = (type == 0) ? qro : kro;
      const float qs = (type == 0) ? QSCALE : 1.0f;
#pragma unroll
      for (int mi = 0; mi < 4; ++mi) {
        const int rb = m0 + wm * 64 + mi * 16 + g * 4;
#pragma unroll
        for (int j = 0; j < 4; ++j) {
          const int row = rb + j;
          if (row < M) {
            const int b_ = row / NL, l = row - b_ * NL;
            const float cf = cosT[l * 16 + c], sf = sinT[l * 16 + c];
            const float a0 = acc[mi][0][j], a1 = acc[mi][1][j];
            const float r0 = (a0 * cf - a1 * sf) * qs;
            const float r1 = (a1 * cf + a0 * sf) * qs;
            const float r2 = acc[mi][2][j] * qs;
            const float r3 = acc[mi][3][j] * qs;
            const size_t bse = ((size_t)(b_ * NHEADS + hd) * NL + l) * 64;
            dst[bse + c]      = (bf16)r0;
            dst[bse + 16 + c] = (bf16)r1;
            dst[bse + 32 + c] = (bf16)r2;
            dst[bse + 48 + c] = (bf16)r3;
          }
        }
      }
    }
  }
}

// ---------------- causal flash attention: dual-tile interleaved, no LDS ----
// One wave per slot; slot s<16 runs tiles {s, 31-s} interleaved in one kv loop;
// slot 16 runs tile 32 alone. P-repack lane exchange via v_permlane32_swap
// (VALU pipe). V clamp hoisted to a wave-uniform branch (only kv0=1024 clamps).
// No setprio (measured regression R9/R15). Base: R16 @421.6us.
__global__ __launch_bounds__(64) void k_attn(const bf16* __restrict__ qr,
                                             const bf16* __restrict__ kr,
                                             const bf16* __restrict__ vt,
                                             bf16* __restrict__ oa) {
  const int bid = blockIdx.x;                    // grid = 4352 = 8 * 544
  const int lbid = (bid & 7) * (NBH * NSLOT / 8) + (bid >> 3);  // XCD-grouped
  const int slot = lbid % NSLOT, bh = lbid / NSLOT;
  const int b = bh >> 4, h = bh & 15;
  const int lane = threadIdx.x;
  const int ql = lane & 31;                      // q-col / kv-row / d-col index
  const int hh = lane >> 5;                      // half (k-chunk selector)
  const bf16* qb = qr + (size_t)bh * NL * 64;
  const bf16* kb = kr + (size_t)bh * NL * 64;
  const bf16* vb = vt + (size_t)bh * 64 * LP;

  const int tA = (slot < 16) ? slot : -1;
  const int tB = (slot < 16) ? 31 - slot : 32;
  const bool hasA = (tA >= 0);

  const int q0A = tA * 32, q0B = tB * 32;
  const int qabsA = q0A + ql, qabsB = q0B + ql;

  bf16x8 bQA[4], bQB[4];
  {
    const int qrB = (q0B + ql < NL) ? q0B + ql : NL - 1;
#pragma unroll
    for (int kc = 0; kc < 4; ++kc)
      bQB[kc] = *(const bf16x8*)(qb + (size_t)qrB * 64 + kc * 16 + hh * 8);
    const int qrA = hasA ? q0A + ql : 0;
#pragma unroll
    for (int kc = 0; kc < 4; ++kc)
      bQA[kc] = *(const bf16x8*)(qb + (size_t)qrA * 64 + kc * 16 + hh * 8);
  }

  f32x16 odA0 = zero16(), odA1 = zero16(), odB0 = zero16(), odB1 = zero16();
  float lsA = 0.f, lsB = 0.f;

  const int ntA = hasA ? ((q0A + 31) / 64 + 1) : 0;
  const int qmaxB = (q0B + 31 < NL - 1) ? q0B + 31 : NL - 1;
  const int ntB = qmaxB / 64 + 1;               // ntA <= ntB always

  bf16x8 aK[2][4];
  auto loadK = [&](int kv0) {
#pragma unroll
    for (int blk = 0; blk < 2; ++blk) {
      int r = kv0 + blk * 32 + ql; if (r >= NL) r = NL - 1;
      const bf16* kp = kb + (size_t)r * 64 + hh * 8;
#pragma unroll
      for (int kc = 0; kc < 4; ++kc)
        aK[blk][kc] = *(const bf16x8*)(kp + kc * 16);
    }
  };
  loadK(0);

  auto smrepack = [&](const f32x16& s0, const f32x16& s1, int kv0, int q0,
                      int qabs, float& ls, bf16x8 (&pa)[4]) {
    const bool needmask = (kv0 + 63 > q0);
#pragma unroll
    for (int blk = 0; blk < 2; ++blk) {
      const f32x16& s = blk ? s1 : s0;
      float p[16];
#pragma unroll
      for (int r = 0; r < 16; ++r) {
        float v = s[r];
        if (needmask) {
          const int kvabs = kv0 + blk * 32 + (r & 3) + 8 * (r >> 2) + 4 * hh;
          if (kvabs > qabs) v = -1e30f;
        }
        p[r] = fexp2(v);
      }
      ls += (((p[0]+p[1])+(p[2]+p[3])) + ((p[4]+p[5])+(p[6]+p[7])))
          + (((p[8]+p[9])+(p[10]+p[11])) + ((p[12]+p[13])+(p[14]+p[15])));
      uint32_t w[8];
#pragma unroll
      for (int a = 0; a < 8; ++a) w[a] = cvtpk(p[2*a], p[2*a+1]);
      // VALU-pipe exchange (replaces 4 DS shuffles):
      uint32_t a0 = w[0], b0 = w[2]; plswap(a0, b0);
      uint32_t a1 = w[1], b1 = w[3]; plswap(a1, b1);
      uint32_t a2 = w[4], b2 = w[6]; plswap(a2, b2);
      uint32_t a3 = w[5], b3 = w[7]; plswap(a3, b3);
      u32x4 w0_, w1_;
      w0_[0] = a0; w0_[1] = a1; w0_[2] = b0; w0_[3] = b1;
      w1_[0] = a2; w1_[1] = a3; w1_[2] = b2; w1_[3] = b3;
      pa[2*blk]     = __builtin_bit_cast(bf16x8, w0_);
      pa[2*blk + 1] = __builtin_bit_cast(bf16x8, w1_);
    }
  };

  for (int tk = 0; tk < ntB; ++tk) {
    const int kv0 = tk * 64;
    const bool actA = hasA && (tk < ntA);

    bf16x8 vf[2][4];
    if (kv0 <= 992) {                         // uniform fast path (no clamp)
#pragma unroll
      for (int dblk = 0; dblk < 2; ++dblk) {
        const bf16* vp = vb + (size_t)(dblk * 32 + ql) * LP + kv0 + hh * 8;
#pragma unroll
        for (int kc = 0; kc < 4; ++kc)
          vf[dblk][kc] = *(const bf16x8*)(vp + kc * 16);
      }
    } else {
#pragma unroll
      for (int dblk = 0; dblk < 2; ++dblk) {
        const bf16* vp = vb + (size_t)(dblk * 32 + ql) * LP;
#pragma unroll
        for (int kc = 0; kc < 4; ++kc) {
          int col = kv0 + kc * 16 + hh * 8;
          if (col > LP - 8) col = LP - 8;     // final-tile clamp (P=0 there)
          vf[dblk][kc] = *(const bf16x8*)(vp + col);
        }
      }
    }

    bf16x8 paA[4];
    if (actA) {
      f32x16 s0 = zero16(), s1 = zero16();
#pragma unroll
      for (int kc = 0; kc < 4; ++kc)
        s0 = __builtin_amdgcn_mfma_f32_32x32x16_bf16(aK[0][kc], bQA[kc], s0, 0, 0, 0);
#pragma unroll
      for (int kc = 0; kc < 4; ++kc)
        s1 = __builtin_amdgcn_mfma_f32_32x32x16_bf16(aK[1][kc], bQA[kc], s1, 0, 0, 0);
      smrepack(s0, s1, kv0, q0A, qabsA, lsA, paA);
    }

    f32x16 sB0 = zero16(), sB1 = zero16();
#pragma unroll
    for (int kc = 0; kc < 4; ++kc)
      sB0 = __builtin_amdgcn_mfma_f32_32x32x16_bf16(aK[0][kc], bQB[kc], sB0, 0, 0, 0);
#pragma unroll
    for (int kc = 0; kc < 4; ++kc)
      sB1 = __builtin_amdgcn_mfma_f32_32x32x16_bf16(aK[1][kc], bQB[kc], sB1, 0, 0, 0);

    if (tk + 1 < ntB) loadK(kv0 + 64);

    if (actA) {
#pragma unroll
      for (int kc = 0; kc < 4; ++kc) {
        odA0 = __builtin_amdgcn_mfma_f32_32x32x16_bf16(paA[kc], vf[0][kc], odA0, 0, 0, 0);
        odA1 = __builtin_amdgcn_mfma_f32_32x32x16_bf16(paA[kc], vf[1][kc], odA1, 0, 0, 0);
      }
    }

    bf16x8 paB[4];
    smrepack(sB0, sB1, kv0, q0B, qabsB, lsB, paB);

#pragma unroll
    for (int kc = 0; kc < 4; ++kc) {
      odB0 = __builtin_amdgcn_mfma_f32_32x32x16_bf16(paB[kc], vf[0][kc], odB0, 0, 0, 0);
      odB1 = __builtin_amdgcn_mfma_f32_32x32x16_bf16(paB[kc], vf[1][kc], odB1, 0, 0, 0);
    }
  }

  auto fin = [&](int q0, float ls, const f32x16& od0, const f32x16& od1) {
    const float tot = ls + __shfl_xor(ls, 32);
    const float invOwn = 1.0f / tot;
#pragma unroll
    for (int r = 0; r < 16; ++r) {
      const int qrl = (r & 3) + 8 * (r >> 2) + 4 * hh;   // local q row of reg r
      const float inv = __shfl(invOwn, qrl);
      const int row = q0 + qrl;
      if (row < NL) {
        const size_t ob = (size_t)(b * NL + row) * NDIM + h * 64;
        oa[ob + ql]      = (bf16)(od0[r] * inv);
        oa[ob + 32 + ql] = (bf16)(od1[r] * inv);
      }
    }
  };
  if (hasA) fin(q0A, lsA, odA0, odA1);
  fin(q0B, lsB, odB0, odB1);
}

extern "C" void kernel_launch(void* const* d_in, const int* in_sizes, int n_in,
                              void* d_out, int out_size, void* d_ws, size_t ws_size,
                              hipStream_t stream) {
  const float* x     = (const float*)d_in[0];
  const float* cond  = (const float*)d_in[1];
  const float* wnorm = (const float*)d_in[2];
  const float* wqkv  = (const float*)d_in[3];
  const float* wout  = (const float*)d_in[4];
  const float* cosT  = (const float*)d_in[5];
  const float* sinT  = (const float*)d_in[6];
  float* out = (float*)d_out;
  char* ws = (char*)d_ws;

  float* s_scl = (float*)(ws);                    //    65,536 B
  bf16*  s_wq  = (bf16*)(ws + 65536);             // 6,291,456 B
  bf16*  s_wo  = (bf16*)(ws + 6356992);           // 2,097,152 B
  bf16*  s_xn  = (bf16*)(ws + 8454144);           // 33,587,200 B (reused as attn out)
  bf16*  s_qr  = (bf16*)(ws + 142802944);         // 33,587,200 B
  bf16*  s_kr  = (bf16*)(ws + 176390144);         // 33,587,200 B
  bf16*  s_vt  = (bf16*)(ws + 209977344);         // 34,603,008 B -> end 244,580,352 B

  k_prep<<<4112, 256, 0, stream>>>(wqkv, wout, cond, wnorm, s_wq, s_wo, s_scl);
  k_rmsnorm<<<NML, 256, 0, stream>>>(x, s_scl, s_xn);
  k_gemm<2><<<3096, 256, 0, stream>>>(s_xn, s_wq, NML, 3 * NDIM, NDIM,
                                      nullptr, nullptr, s_qr, s_kr, s_vt,
                                      cosT, sinT);
  k_attn<<<NBH * NSLOT, 64, 0, stream>>>(s_qr, s_kr, s_vt, s_xn);
  k_gemm<1><<<1032, 256, 0, stream>>>(s_xn, s_wo, NML, NDIM, NDIM,
                                      out, x, nullptr, nullptr, nullptr,
                                      nullptr, nullptr);
}

// Round 20
// 408.999 us; speedup vs baseline: 1.0415x; 1.0359x over previous
//
#include <hip/hip_runtime.h>
#include <hip/hip_bf16.h>
#include <cstdint>

typedef __bf16 bf16;
typedef bf16 bf16x4 __attribute__((ext_vector_type(4)));
typedef bf16 bf16x8 __attribute__((ext_vector_type(8)));
typedef float f32x4 __attribute__((ext_vector_type(4)));
typedef float f32x16 __attribute__((ext_vector_type(16)));
typedef uint32_t u32x4 __attribute__((ext_vector_type(4)));

#define NB 16
#define NL 1025
#define NDIM 1024
#define NHEADS 16
#define NCOND 256
#define NBH (NB*NHEADS)       // 256
#define NML (NB*NL)           // 16400
#define LP 1056               // padded kv length for v^T rows
#define NSLOT 17              // attn: balanced 32-row q-tile slots per bh
#define QSCALE (0.125f * 1.44269504088896340736f)  // sm_scale * log2(e)

__device__ __forceinline__ void gload16(const void* g, void* l) {
  __builtin_amdgcn_global_load_lds(
      (const __attribute__((address_space(1))) void*)(uintptr_t)g,
      (__attribute__((address_space(3))) void*)(uintptr_t)l,
      16, 0, 0);
}

__device__ __forceinline__ float fexp2(float x) {
  return __builtin_amdgcn_exp2f(x);   // raw v_exp_f32; exp2(-1e30) -> 0
}

__device__ __forceinline__ uint32_t cvtpk(float lo, float hi) {
  uint32_t r;
  asm("v_cvt_pk_bf16_f32 %0, %1, %2" : "=v"(r) : "v"(lo), "v"(hi));
  return r;   // lo -> bits [15:0], hi -> bits [31:16]
}

// lane[i] <-> lane[i+32] pairwise exchange on the VALU pipe (T12).
__device__ __forceinline__ void plswap(uint32_t& a, uint32_t& b) {
  asm volatile("v_permlane32_swap_b32 %0, %1" : "+v"(a), "+v"(b));
}

__device__ __forceinline__ f32x16 zero16() {
  f32x16 z;
#pragma unroll
  for (int i = 0; i < 16; ++i) z[i] = 0.f;
  return z;
}

// ---------------- merged prep: cast wqkv, cast wout, cond scale ----------------
// blocks [0,3072): wqkv cast; [3072,4096): wout cast; [4096,4112): scale rows.
__global__ __launch_bounds__(256) void k_prep(const float* __restrict__ wqkv,
                                              const float* __restrict__ wout,
                                              const float* __restrict__ cond,
                                              const float* __restrict__ wn,
                                              bf16* __restrict__ wq,
                                              bf16* __restrict__ wo,
                                              float* __restrict__ scl) {
  __shared__ float cs[NCOND];
  const int bid = blockIdx.x, t = threadIdx.x;
  if (bid < 4096) {
    const float* src = (bid < 3072) ? wqkv : wout;
    bf16* dst = (bid < 3072) ? wq : wo;
    const int lb = (bid < 3072) ? bid : bid - 3072;
    const int i = (lb * 256 + t) * 4;
    float4 v = *(const float4*)(src + i);
    bf16x4 o;
    o[0] = (bf16)v.x; o[1] = (bf16)v.y; o[2] = (bf16)v.z; o[3] = (bf16)v.w;
    *(bf16x4*)(dst + i) = o;
  } else {
    const int b = bid - 4096;
    cs[t] = cond[b * NCOND + t];
    __syncthreads();
#pragma unroll
    for (int dd = 0; dd < 4; ++dd) {
      const int d = t * 4 + dd;
      const float4* w = (const float4*)(wn + (size_t)d * NCOND);
      float acc = 1.0f;
      for (int c4 = 0; c4 < NCOND / 4; ++c4) {
        float4 wv = w[c4];
        acc += wv.x * cs[c4*4] + wv.y * cs[c4*4+1] + wv.z * cs[c4*4+2] + wv.w * cs[c4*4+3];
      }
      scl[b * NDIM + d] = acc;
    }
  }
}

// ---------------- RMSNorm * scale -> xn (bf16) ----------------
// R16-proven block-per-row version.
__global__ __launch_bounds__(256) void k_rmsnorm(const float* __restrict__ x,
                                                 const float* __restrict__ scl,
                                                 bf16* __restrict__ xn) {
  const int row = blockIdx.x, t = threadIdx.x;
  const int b = row / NL;
  const float* xr = x + (size_t)row * NDIM;
  float4 v = *(const float4*)(xr + t * 4);
  float ss = v.x*v.x + v.y*v.y + v.z*v.z + v.w*v.w;
#pragma unroll
  for (int o = 1; o < 64; o <<= 1) ss += __shfl_xor(ss, o);
  __shared__ float red[4];
  if ((t & 63) == 0) red[t >> 6] = ss;
  __syncthreads();
  const float tot = red[0] + red[1] + red[2] + red[3];
  const float rn = rsqrtf(tot * (1.0f / NDIM) + 1e-6f);
  const float4 sc = *(const float4*)(scl + b * NDIM + t * 4);
  bf16x4 o4;
  o4[0] = (bf16)(v.x * sc.x * rn);
  o4[1] = (bf16)(v.y * sc.y * rn);
  o4[2] = (bf16)(v.z * sc.z * rn);
  o4[3] = (bf16)(v.w * sc.w * rn);
  *(bf16x4*)(xn + (size_t)row * NDIM + t * 4) = o4;
}

// ---------------- GEMM: C[m,n] = sum_k A[m,k]*B[n,k]  (both row-major, B^T) ----
// R12-proven config: 128x128 tile, 4 waves, BK=64, 2-buffer counted-vmcnt
// pipeline { stage(t+1); vmcnt(8); barrier; ds_read+MFMA (setprio); barrier },
// XOR-granule swizzle (0 bank conflicts), bijective XCD-grouped 1D grid.
// EPI=1: store f32 + skip add. EPI=2: fused RoPE/layout epilogue; q/k writes
// vectorized via per-wave private LDS transpose (staging LDS is dead after the
// final main-loop barrier; regions disjoint per wave -> no extra barriers).
template <int EPI>
__global__ __launch_bounds__(256) void k_gemm(const bf16* __restrict__ A,
                                              const bf16* __restrict__ Bm,
                                              int M, int N, int K,
                                              float* __restrict__ Cf,
                                              const float* __restrict__ skip,
                                              bf16* __restrict__ qro,
                                              bf16* __restrict__ kro,
                                              bf16* __restrict__ vto,
                                              const float* __restrict__ cosT,
                                              const float* __restrict__ sinT) {
  __shared__ bf16 Als[2][128 * 64];
  __shared__ bf16 Bls[2][128 * 64];
  const int t = threadIdx.x;
  const int wave = t >> 6, lane = t & 63;
  const int g = lane >> 4, c = lane & 15;
  const int wm = wave >> 1, wn_ = wave & 1;

  const int nxb = N >> 7;
  const int nwg = gridDim.x;
  const int cpx = nwg >> 3;
  const int bid = blockIdx.x;
  const int swz = (nwg & 7) ? bid : (bid & 7) * cpx + (bid >> 3);  // XCD-grouped
  const int m0 = (swz / nxb) * 128, n0 = (swz % nxb) * 128;
  const int NT = K >> 6;

  const int srow = lane >> 3;                 // row within 8-row segment
  const int scol = ((lane & 7) ^ srow) * 8;   // pre-swizzled source granule

  f32x4 acc[4][4];
#pragma unroll
  for (int i = 0; i < 4; ++i)
#pragma unroll
    for (int j = 0; j < 4; ++j) acc[i][j] = f32x4{0.f, 0.f, 0.f, 0.f};

  auto stage = [&](int kt, int q) {
    const int k0 = kt << 6;
#pragma unroll
    for (int i = 0; i < 4; ++i) {
      const int seg = wave * 4 + i;
      int arow = m0 + seg * 8 + srow;
      if (arow >= M) arow = M - 1;
      gload16(A + (size_t)arow * K + k0 + scol, &Als[q][seg * 512]);
      const int brow = n0 + seg * 8 + srow;   // N % 128 == 0, no clamp
      gload16(Bm + (size_t)brow * K + k0 + scol, &Bls[q][seg * 512]);
    }
  };

  stage(0, 0);                                 // 8 loads in flight
  for (int kt = 0; kt < NT; ++kt) {
    const int cur = kt & 1;
    if (kt + 1 < NT) {
      stage(kt + 1, cur ^ 1);                  // 16 in flight
      asm volatile("s_waitcnt vmcnt(8)" ::: "memory");  // stage(kt) retired
    } else {
      asm volatile("s_waitcnt vmcnt(0)" ::: "memory");  // tail drain
    }
    __builtin_amdgcn_s_barrier();              // all waves' stage(kt) visible
    asm volatile("" ::: "memory");
#pragma unroll
    for (int kc = 0; kc < 2; ++kc) {
      bf16x8 af[4], bfr[4];
#pragma unroll
      for (int mi = 0; mi < 4; ++mi) {
        const int r = wm * 64 + mi * 16 + c;
        const int gg = ((kc * 4 + g) ^ (c & 7)) * 8;
        af[mi] = *(const bf16x8*)&Als[cur][r * 64 + gg];
      }
#pragma unroll
      for (int ni = 0; ni < 4; ++ni) {
        const int r = wn_ * 64 + ni * 16 + c;
        const int gg = ((kc * 4 + g) ^ (c & 7)) * 8;
        bfr[ni] = *(const bf16x8*)&Bls[cur][r * 64 + gg];
      }
      __builtin_amdgcn_s_setprio(1);
#pragma unroll
      for (int mi = 0; mi < 4; ++mi)
#pragma unroll
        for (int ni = 0; ni < 4; ++ni)
          acc[mi][ni] = __builtin_amdgcn_mfma_f32_16x16x32_bf16(af[mi], bfr[ni], acc[mi][ni], 0, 0, 0);
      __builtin_amdgcn_s_setprio(0);
    }
    asm volatile("" ::: "memory");
    __builtin_amdgcn_s_barrier();              // reads of buf done before overwrite
  }

  if (EPI == 1) {
#pragma unroll
    for (int mi = 0; mi < 4; ++mi) {
      const int rb = m0 + wm * 64 + mi * 16 + g * 4;
#pragma unroll
      for (int ni = 0; ni < 4; ++ni) {
        const int col = n0 + wn_ * 64 + ni * 16 + c;
#pragma unroll
        for (int j = 0; j < 4; ++j) {
          const int row = rb + j;
          if (row < M) {
            const size_t idx = (size_t)row * N + col;
            Cf[idx] = acc[mi][ni][j] + skip[idx];
          }
        }
      }
    }
  } else {
    // EPI==2: fused RoPE + layout epilogue
    const int ncol0 = n0 + wn_ * 64;
    const int type = ncol0 >> 10;              // 0=q, 1=k, 2=v
    const int hd = (ncol0 & 1023) >> 6;        // head
    if (type == 2) {
      // V: vt[bh][d][LP] with d = ni*16+c; 4 consecutive l per (mi) -> bf16x4
#pragma unroll
      for (int mi = 0; mi < 4; ++mi) {
        const int rb = m0 + wm * 64 + mi * 16 + g * 4;
        const int b0 = rb / NL, b3 = (rb + 3) / NL;
        if (rb + 3 < M && b0 == b3) {
          const int l0_ = rb - b0 * NL;
          const size_t bhb = (size_t)(b0 * NHEADS + hd) * 64;
#pragma unroll
          for (int ni = 0; ni < 4; ++ni) {
            const int d = ni * 16 + c;
            bf16x4 v4;
#pragma unroll
            for (int j = 0; j < 4; ++j) v4[j] = (bf16)acc[mi][ni][j];
            *(bf16x4*)(vto + (bhb + d) * LP + l0_) = v4;
          }
        } else {
#pragma unroll
          for (int j = 0; j < 4; ++j) {
            const int row = rb + j;
            if (row < M) {
              const int b_ = row / NL, l = row - b_ * NL;
              const size_t bhb = (size_t)(b_ * NHEADS + hd) * 64;
#pragma unroll
              for (int ni = 0; ni < 4; ++ni)
                vto[(bhb + ni * 16 + c) * LP + l] = (bf16)acc[mi][ni][j];
            }
          }
        }
      }
    } else {
      bf16* dst = (type == 0) ? qro : kro;
      const float qs = (type == 0) ? QSCALE : 1.0f;
      // Per-wave private LDS transpose buffer: 64 x 72 bf16 (pad +8 -> +4-bank
      // row shift). Waves 0,1 live in Als; waves 2,3 in Bls. Staging LDS is
      // dead here (final main-loop barrier passed); regions disjoint per wave.
      bf16* T = (wave < 2) ? (&Als[0][0] + wave * 4608)
                           : (&Bls[0][0] + (wave - 2) * 4608);
#pragma unroll
      for (int mi = 0; mi < 4; ++mi) {
#pragma unroll
        for (int j = 0; j < 4; ++j) {
          const int rowL = mi * 16 + g * 4 + j;
          const int rowG = m0 + wm * 64 + rowL;
          const int l = rowG - (rowG / NL) * NL;   // in [0, NL) even past M
          const float cf = cosT[l * 16 + c], sf = sinT[l * 16 + c];
          const float a0 = acc[mi][0][j], a1 = acc[mi][1][j];
          T[rowL * 72 + c]      = (bf16)((a0 * cf - a1 * sf) * qs);
          T[rowL * 72 + 16 + c] = (bf16)((a1 * cf + a0 * sf) * qs);
          T[rowL * 72 + 32 + c] = (bf16)(acc[mi][2][j] * qs);
          T[rowL * 72 + 48 + c] = (bf16)(acc[mi][3][j] * qs);
        }
      }
      // coalesced store: lanes 0..7 cover one full 128B row
#pragma unroll
      for (int i = 0; i < 8; ++i) {
        const int rowL = i * 8 + (lane >> 3);
        const int rowG = m0 + wm * 64 + rowL;
        if (rowG < M) {
          const int b_ = rowG / NL, l = rowG - b_ * NL;
          const size_t bse = ((size_t)(b_ * NHEADS + hd) * NL + l) * 64;
          const int ch = (lane & 7) * 8;
          *(bf16x8*)(dst + bse + ch) = *(const bf16x8*)&T[rowL * 72 + ch];
        }
      }
    }
  }
}

// ---------------- causal flash attention: dual-tile interleaved, no LDS ----
// One wave per slot; slot s<16 runs tiles {s, 31-s} interleaved in one kv loop;
// slot 16 runs tile 32 alone. P-repack lane exchange via v_permlane32_swap
// (VALU pipe). V clamp hoisted to a wave-uniform branch (only kv0=1024 clamps).
// No setprio (measured regression R9/R15). Base: R16 @421.6us / R19 @423.7us.
__global__ __launch_bounds__(64) void k_attn(const bf16* __restrict__ qr,
                                             const bf16* __restrict__ kr,
                                             const bf16* __restrict__ vt,
                                             bf16* __restrict__ oa) {
  const int bid = blockIdx.x;                    // grid = 4352 = 8 * 544
  const int lbid = (bid & 7) * (NBH * NSLOT / 8) + (bid >> 3);  // XCD-grouped
  const int slot = lbid % NSLOT, bh = lbid / NSLOT;
  const int b = bh >> 4, h = bh & 15;
  const int lane = threadIdx.x;
  const int ql = lane & 31;                      // q-col / kv-row / d-col index
  const int hh = lane >> 5;                      // half (k-chunk selector)
  const bf16* qb = qr + (size_t)bh * NL * 64;
  const bf16* kb = kr + (size_t)bh * NL * 64;
  const bf16* vb = vt + (size_t)bh * 64 * LP;

  const int tA = (slot < 16) ? slot : -1;
  const int tB = (slot < 16) ? 31 - slot : 32;
  const bool hasA = (tA >= 0);

  const int q0A = tA * 32, q0B = tB * 32;
  const int qabsA = q0A + ql, qabsB = q0B + ql;

  bf16x8 bQA[4], bQB[4];
  {
    const int qrB = (q0B + ql < NL) ? q0B + ql : NL - 1;
#pragma unroll
    for (int kc = 0; kc < 4; ++kc)
      bQB[kc] = *(const bf16x8*)(qb + (size_t)qrB * 64 + kc * 16 + hh * 8);
    const int qrA = hasA ? q0A + ql : 0;
#pragma unroll
    for (int kc = 0; kc < 4; ++kc)
      bQA[kc] = *(const bf16x8*)(qb + (size_t)qrA * 64 + kc * 16 + hh * 8);
  }

  f32x16 odA0 = zero16(), odA1 = zero16(), odB0 = zero16(), odB1 = zero16();
  float lsA = 0.f, lsB = 0.f;

  const int ntA = hasA ? ((q0A + 31) / 64 + 1) : 0;
  const int qmaxB = (q0B + 31 < NL - 1) ? q0B + 31 : NL - 1;
  const int ntB = qmaxB / 64 + 1;               // ntA <= ntB always

  bf16x8 aK[2][4];
  auto loadK = [&](int kv0) {
#pragma unroll
    for (int blk = 0; blk < 2; ++blk) {
      int r = kv0 + blk * 32 + ql; if (r >= NL) r = NL - 1;
      const bf16* kp = kb + (size_t)r * 64 + hh * 8;
#pragma unroll
      for (int kc = 0; kc < 4; ++kc)
        aK[blk][kc] = *(const bf16x8*)(kp + kc * 16);
    }
  };
  loadK(0);

  auto smrepack = [&](const f32x16& s0, const f32x16& s1, int kv0, int q0,
                      int qabs, float& ls, bf16x8 (&pa)[4]) {
    const bool needmask = (kv0 + 63 > q0);
#pragma unroll
    for (int blk = 0; blk < 2; ++blk) {
      const f32x16& s = blk ? s1 : s0;
      float p[16];
#pragma unroll
      for (int r = 0; r < 16; ++r) {
        float v = s[r];
        if (needmask) {
          const int kvabs = kv0 + blk * 32 + (r & 3) + 8 * (r >> 2) + 4 * hh;
          if (kvabs > qabs) v = -1e30f;
        }
        p[r] = fexp2(v);
      }
      ls += (((p[0]+p[1])+(p[2]+p[3])) + ((p[4]+p[5])+(p[6]+p[7])))
          + (((p[8]+p[9])+(p[10]+p[11])) + ((p[12]+p[13])+(p[14]+p[15])));
      uint32_t w[8];
#pragma unroll
      for (int a = 0; a < 8; ++a) w[a] = cvtpk(p[2*a], p[2*a+1]);
      // VALU-pipe exchange (replaces 4 DS shuffles):
      uint32_t a0 = w[0], b0 = w[2]; plswap(a0, b0);
      uint32_t a1 = w[1], b1 = w[3]; plswap(a1, b1);
      uint32_t a2 = w[4], b2 = w[6]; plswap(a2, b2);
      uint32_t a3 = w[5], b3 = w[7]; plswap(a3, b3);
      u32x4 w0_, w1_;
      w0_[0] = a0; w0_[1] = a1; w0_[2] = b0; w0_[3] = b1;
      w1_[0] = a2; w1_[1] = a3; w1_[2] = b2; w1_[3] = b3;
      pa[2*blk]     = __builtin_bit_cast(bf16x8, w0_);
      pa[2*blk + 1] = __builtin_bit_cast(bf16x8, w1_);
    }
  };

  for (int tk = 0; tk < ntB; ++tk) {
    const int kv0 = tk * 64;
    const bool actA = hasA && (tk < ntA);

    bf16x8 vf[2][4];
    if (kv0 <= 992) {                         // uniform fast path (no clamp)
#pragma unroll
      for (int dblk = 0; dblk < 2; ++dblk) {
        const bf16* vp = vb + (size_t)(dblk * 32 + ql) * LP + kv0 + hh * 8;
#pragma unroll
        for (int kc = 0; kc < 4; ++kc)
          vf[dblk][kc] = *(const bf16x8*)(vp + kc * 16);
      }
    } else {
#pragma unroll
      for (int dblk = 0; dblk < 2; ++dblk) {
        const bf16* vp = vb + (size_t)(dblk * 32 + ql) * LP;
#pragma unroll
        for (int kc = 0; kc < 4; ++kc) {
          int col = kv0 + kc * 16 + hh * 8;
          if (col > LP - 8) col = LP - 8;     // final-tile clamp (P=0 there)
          vf[dblk][kc] = *(const bf16x8*)(vp + col);
        }
      }
    }

    bf16x8 paA[4];
    if (actA) {
      f32x16 s0 = zero16(), s1 = zero16();
#pragma unroll
      for (int kc = 0; kc < 4; ++kc)
        s0 = __builtin_amdgcn_mfma_f32_32x32x16_bf16(aK[0][kc], bQA[kc], s0, 0, 0, 0);
#pragma unroll
      for (int kc = 0; kc < 4; ++kc)
        s1 = __builtin_amdgcn_mfma_f32_32x32x16_bf16(aK[1][kc], bQA[kc], s1, 0, 0, 0);
      smrepack(s0, s1, kv0, q0A, qabsA, lsA, paA);
    }

    f32x16 sB0 = zero16(), sB1 = zero16();
#pragma unroll
    for (int kc = 0; kc < 4; ++kc)
      sB0 = __builtin_amdgcn_mfma_f32_32x32x16_bf16(aK[0][kc], bQB[kc], sB0, 0, 0, 0);
#pragma unroll
    for (int kc = 0; kc < 4; ++kc)
      sB1 = __builtin_amdgcn_mfma_f32_32x32x16_bf16(aK[1][kc], bQB[kc], sB1, 0, 0, 0);

    if (tk + 1 < ntB) loadK(kv0 + 64);

    if (actA) {
#pragma unroll
      for (int kc = 0; kc < 4; ++kc) {
        odA0 = __builtin_amdgcn_mfma_f32_32x32x16_bf16(paA[kc], vf[0][kc], odA0, 0, 0, 0);
        odA1 = __builtin_amdgcn_mfma_f32_32x32x16_bf16(paA[kc], vf[1][kc], odA1, 0, 0, 0);
      }
    }

    bf16x8 paB[4];
    smrepack(sB0, sB1, kv0, q0B, qabsB, lsB, paB);

#pragma unroll
    for (int kc = 0; kc < 4; ++kc) {
      odB0 = __builtin_amdgcn_mfma_f32_32x32x16_bf16(paB[kc], vf[0][kc], odB0, 0, 0, 0);
      odB1 = __builtin_amdgcn_mfma_f32_32x32x16_bf16(paB[kc], vf[1][kc], odB1, 0, 0, 0);
    }
  }

  auto fin = [&](int q0, float ls, const f32x16& od0, const f32x16& od1) {
    const float tot = ls + __shfl_xor(ls, 32);
    const float invOwn = 1.0f / tot;
#pragma unroll
    for (int r = 0; r < 16; ++r) {
      const int qrl = (r & 3) + 8 * (r >> 2) + 4 * hh;   // local q row of reg r
      const float inv = __shfl(invOwn, qrl);
      const int row = q0 + qrl;
      if (row < NL) {
        const size_t ob = (size_t)(b * NL + row) * NDIM + h * 64;
        oa[ob + ql]      = (bf16)(od0[r] * inv);
        oa[ob + 32 + ql] = (bf16)(od1[r] * inv);
      }
    }
  };
  if (hasA) fin(q0A, lsA, odA0, odA1);
  fin(q0B, lsB, odB0, odB1);
}

extern "C" void kernel_launch(void* const* d_in, const int* in_sizes, int n_in,
                              void* d_out, int out_size, void* d_ws, size_t ws_size,
                              hipStream_t stream) {
  const float* x     = (const float*)d_in[0];
  const float* cond  = (const float*)d_in[1];
  const float* wnorm = (const float*)d_in[2];
  const float* wqkv  = (const float*)d_in[3];
  const float* wout  = (const float*)d_in[4];
  const float* cosT  = (const float*)d_in[5];
  const float* sinT  = (const float*)d_in[6];
  float* out = (float*)d_out;
  char* ws = (char*)d_ws;

  float* s_scl = (float*)(ws);                    //    65,536 B
  bf16*  s_wq  = (bf16*)(ws + 65536);             // 6,291,456 B
  bf16*  s_wo  = (bf16*)(ws + 6356992);           // 2,097,152 B
  bf16*  s_xn  = (bf16*)(ws + 8454144);           // 33,587,200 B (reused as attn out)
  bf16*  s_qr  = (bf16*)(ws + 142802944);         // 33,587,200 B
  bf16*  s_kr  = (bf16*)(ws + 176390144);         // 33,587,200 B
  bf16*  s_vt  = (bf16*)(ws + 209977344);         // 34,603,008 B -> end 244,580,352 B

  k_prep<<<4112, 256, 0, stream>>>(wqkv, wout, cond, wnorm, s_wq, s_wo, s_scl);
  k_rmsnorm<<<NML, 256, 0, stream>>>(x, s_scl, s_xn);
  k_gemm<2><<<3096, 256, 0, stream>>>(s_xn, s_wq, NML, 3 * NDIM, NDIM,
                                      nullptr, nullptr, s_qr, s_kr, s_vt,
                                      cosT, sinT);
  k_attn<<<NBH * NSLOT, 64, 0, stream>>>(s_qr, s_kr, s_vt, s_xn);
  k_gemm<1><<<1032, 256, 0, stream>>>(s_xn, s_wo, NML, NDIM, NDIM,
                                      out, x, nullptr, nullptr, nullptr,
                                      nullptr, nullptr);
}

// Round 21
// 384.367 us; speedup vs baseline: 1.1082x; 1.0641x over previous
//
#include <hip/hip_runtime.h>
#include <hip/hip_bf16.h>
#include <cstdint>

typedef __bf16 bf16;
typedef bf16 bf16x4 __attribute__((ext_vector_type(4)));
typedef bf16 bf16x8 __attribute__((ext_vector_type(8)));
typedef float f32x4 __attribute__((ext_vector_type(4)));
typedef float f32x16 __attribute__((ext_vector_type(16)));
typedef uint32_t u32x4 __attribute__((ext_vector_type(4)));

#define NB 16
#define NL 1025
#define NDIM 1024
#define NHEADS 16
#define NCOND 256
#define NBH (NB*NHEADS)       // 256
#define NML (NB*NL)           // 16400
#define LP 1056               // padded kv length for v^T rows
#define NSLOT 17              // attn: balanced 32-row q-tile slots per bh
#define QSCALE (0.125f * 1.44269504088896340736f)  // sm_scale * log2(e)

__device__ __forceinline__ void gload16(const void* g, void* l) {
  __builtin_amdgcn_global_load_lds(
      (const __attribute__((address_space(1))) void*)(uintptr_t)g,
      (__attribute__((address_space(3))) void*)(uintptr_t)l,
      16, 0, 0);
}

__device__ __forceinline__ float fexp2(float x) {
  return __builtin_amdgcn_exp2f(x);   // raw v_exp_f32; exp2(-1e30) -> 0
}

__device__ __forceinline__ uint32_t cvtpk(float lo, float hi) {
  uint32_t r;
  asm("v_cvt_pk_bf16_f32 %0, %1, %2" : "=v"(r) : "v"(lo), "v"(hi));
  return r;   // lo -> bits [15:0], hi -> bits [31:16]
}

// lane[i] <-> lane[i+32] pairwise exchange on the VALU pipe (T12).
__device__ __forceinline__ void plswap(uint32_t& a, uint32_t& b) {
  asm volatile("v_permlane32_swap_b32 %0, %1" : "+v"(a), "+v"(b));
}

__device__ __forceinline__ f32x16 zero16() {
  f32x16 z;
#pragma unroll
  for (int i = 0; i < 16; ++i) z[i] = 0.f;
  return z;
}

// ---------------- merged prep: cast wqkv, cast wout, cond scale ----------------
// blocks [0,3072): wqkv cast; [3072,4096): wout cast; [4096,4112): scale rows.
__global__ __launch_bounds__(256) void k_prep(const float* __restrict__ wqkv,
                                              const float* __restrict__ wout,
                                              const float* __restrict__ cond,
                                              const float* __restrict__ wn,
                                              bf16* __restrict__ wq,
                                              bf16* __restrict__ wo,
                                              float* __restrict__ scl) {
  __shared__ float cs[NCOND];
  const int bid = blockIdx.x, t = threadIdx.x;
  if (bid < 4096) {
    const float* src = (bid < 3072) ? wqkv : wout;
    bf16* dst = (bid < 3072) ? wq : wo;
    const int lb = (bid < 3072) ? bid : bid - 3072;
    const int i = (lb * 256 + t) * 4;
    float4 v = *(const float4*)(src + i);
    bf16x4 o;
    o[0] = (bf16)v.x; o[1] = (bf16)v.y; o[2] = (bf16)v.z; o[3] = (bf16)v.w;
    *(bf16x4*)(dst + i) = o;
  } else {
    const int b = bid - 4096;
    cs[t] = cond[b * NCOND + t];
    __syncthreads();
#pragma unroll
    for (int dd = 0; dd < 4; ++dd) {
      const int d = t * 4 + dd;
      const float4* w = (const float4*)(wn + (size_t)d * NCOND);
      float acc = 1.0f;
      for (int c4 = 0; c4 < NCOND / 4; ++c4) {
        float4 wv = w[c4];
        acc += wv.x * cs[c4*4] + wv.y * cs[c4*4+1] + wv.z * cs[c4*4+2] + wv.w * cs[c4*4+3];
      }
      scl[b * NDIM + d] = acc;
    }
  }
}

// ---------------- RMSNorm * scale -> xn (bf16) ----------------
__global__ __launch_bounds__(256) void k_rmsnorm(const float* __restrict__ x,
                                                 const float* __restrict__ scl,
                                                 bf16* __restrict__ xn) {
  const int row = blockIdx.x, t = threadIdx.x;
  const int b = row / NL;
  const float* xr = x + (size_t)row * NDIM;
  float4 v = *(const float4*)(xr + t * 4);
  float ss = v.x*v.x + v.y*v.y + v.z*v.z + v.w*v.w;
#pragma unroll
  for (int o = 1; o < 64; o <<= 1) ss += __shfl_xor(ss, o);
  __shared__ float red[4];
  if ((t & 63) == 0) red[t >> 6] = ss;
  __syncthreads();
  const float tot = red[0] + red[1] + red[2] + red[3];
  const float rn = rsqrtf(tot * (1.0f / NDIM) + 1e-6f);
  const float4 sc = *(const float4*)(scl + b * NDIM + t * 4);
  bf16x4 o4;
  o4[0] = (bf16)(v.x * sc.x * rn);
  o4[1] = (bf16)(v.y * sc.y * rn);
  o4[2] = (bf16)(v.z * sc.z * rn);
  o4[3] = (bf16)(v.w * sc.w * rn);
  *(bf16x4*)(xn + (size_t)row * NDIM + t * 4) = o4;
}

// ---------------- GEMM: C[m,n] = sum_k A[m,k]*B[n,k]  (both row-major, B^T) ----
// R12-proven config: 128x128 tile, 4 waves, BK=64, 2-buffer counted-vmcnt
// pipeline { stage(t+1); vmcnt(8); barrier; ds_read+MFMA (setprio); barrier },
// XOR-granule swizzle (0 bank conflicts), bijective XCD-grouped 1D grid.
// EPI=1: skip-add + f32 store, vectorized via per-wave LDS transpose (2 passes
//        of 32 rows, f32 buffer 32x68 pad -> 2-way-only write conflicts).
// EPI=2: fused RoPE/layout epilogue; q/k writes vectorized via per-wave LDS
//        transpose (R20-proven). Staging LDS dead after final main-loop barrier.
template <int EPI>
__global__ __launch_bounds__(256) void k_gemm(const bf16* __restrict__ A,
                                              const bf16* __restrict__ Bm,
                                              int M, int N, int K,
                                              float* __restrict__ Cf,
                                              const float* __restrict__ skip,
                                              bf16* __restrict__ qro,
                                              bf16* __restrict__ kro,
                                              bf16* __restrict__ vto,
                                              const float* __restrict__ cosT,
                                              const float* __restrict__ sinT) {
  __shared__ bf16 Als[2][128 * 64];
  __shared__ bf16 Bls[2][128 * 64];
  const int t = threadIdx.x;
  const int wave = t >> 6, lane = t & 63;
  const int g = lane >> 4, c = lane & 15;
  const int wm = wave >> 1, wn_ = wave & 1;

  const int nxb = N >> 7;
  const int nwg = gridDim.x;
  const int cpx = nwg >> 3;
  const int bid = blockIdx.x;
  const int swz = (nwg & 7) ? bid : (bid & 7) * cpx + (bid >> 3);  // XCD-grouped
  const int m0 = (swz / nxb) * 128, n0 = (swz % nxb) * 128;
  const int NT = K >> 6;

  const int srow = lane >> 3;                 // row within 8-row segment
  const int scol = ((lane & 7) ^ srow) * 8;   // pre-swizzled source granule

  f32x4 acc[4][4];
#pragma unroll
  for (int i = 0; i < 4; ++i)
#pragma unroll
    for (int j = 0; j < 4; ++j) acc[i][j] = f32x4{0.f, 0.f, 0.f, 0.f};

  auto stage = [&](int kt, int q) {
    const int k0 = kt << 6;
#pragma unroll
    for (int i = 0; i < 4; ++i) {
      const int seg = wave * 4 + i;
      int arow = m0 + seg * 8 + srow;
      if (arow >= M) arow = M - 1;
      gload16(A + (size_t)arow * K + k0 + scol, &Als[q][seg * 512]);
      const int brow = n0 + seg * 8 + srow;   // N % 128 == 0, no clamp
      gload16(Bm + (size_t)brow * K + k0 + scol, &Bls[q][seg * 512]);
    }
  };

  stage(0, 0);                                 // 8 loads in flight
  for (int kt = 0; kt < NT; ++kt) {
    const int cur = kt & 1;
    if (kt + 1 < NT) {
      stage(kt + 1, cur ^ 1);                  // 16 in flight
      asm volatile("s_waitcnt vmcnt(8)" ::: "memory");  // stage(kt) retired
    } else {
      asm volatile("s_waitcnt vmcnt(0)" ::: "memory");  // tail drain
    }
    __builtin_amdgcn_s_barrier();              // all waves' stage(kt) visible
    asm volatile("" ::: "memory");
#pragma unroll
    for (int kc = 0; kc < 2; ++kc) {
      bf16x8 af[4], bfr[4];
#pragma unroll
      for (int mi = 0; mi < 4; ++mi) {
        const int r = wm * 64 + mi * 16 + c;
        const int gg = ((kc * 4 + g) ^ (c & 7)) * 8;
        af[mi] = *(const bf16x8*)&Als[cur][r * 64 + gg];
      }
#pragma unroll
      for (int ni = 0; ni < 4; ++ni) {
        const int r = wn_ * 64 + ni * 16 + c;
        const int gg = ((kc * 4 + g) ^ (c & 7)) * 8;
        bfr[ni] = *(const bf16x8*)&Bls[cur][r * 64 + gg];
      }
      __builtin_amdgcn_s_setprio(1);
#pragma unroll
      for (int mi = 0; mi < 4; ++mi)
#pragma unroll
        for (int ni = 0; ni < 4; ++ni)
          acc[mi][ni] = __builtin_amdgcn_mfma_f32_16x16x32_bf16(af[mi], bfr[ni], acc[mi][ni], 0, 0, 0);
      __builtin_amdgcn_s_setprio(0);
    }
    asm volatile("" ::: "memory");
    __builtin_amdgcn_s_barrier();              // reads of buf done before overwrite
  }

  if (EPI == 1) {
    // Per-wave private f32 LDS transpose, two passes of 32 rows (8704 B/wave).
    float* T = (wave < 2) ? (float*)((char*)&Als[0][0] + wave * 8704)
                          : (float*)((char*)&Bls[0][0] + (wave - 2) * 8704);
#pragma unroll
    for (int pass = 0; pass < 2; ++pass) {
#pragma unroll
      for (int ml = 0; ml < 2; ++ml) {
        const int mi = pass * 2 + ml;
#pragma unroll
        for (int ni = 0; ni < 4; ++ni)
#pragma unroll
          for (int j = 0; j < 4; ++j)
            T[(ml * 16 + g * 4 + j) * 68 + ni * 16 + c] = acc[mi][ni][j];
      }
      // read + vectorized skip add + float4 stores; 8 lanes cover a 256B row run
#pragma unroll
      for (int i = 0; i < 4; ++i) {
        const int rowL = i * 8 + (lane >> 3);
        const int rowG = m0 + wm * 64 + pass * 32 + rowL;
        if (rowG < M) {
          const int ch = (lane & 7) * 8;
          const size_t idx = (size_t)rowG * N + n0 + wn_ * 64 + ch;
          const float4 s0 = *(const float4*)(skip + idx);
          const float4 s1 = *(const float4*)(skip + idx + 4);
          const float* Tr = &T[rowL * 68 + ch];
          float4 v0, v1;
          v0.x = Tr[0] + s0.x; v0.y = Tr[1] + s0.y;
          v0.z = Tr[2] + s0.z; v0.w = Tr[3] + s0.w;
          v1.x = Tr[4] + s1.x; v1.y = Tr[5] + s1.y;
          v1.z = Tr[6] + s1.z; v1.w = Tr[7] + s1.w;
          *(float4*)(Cf + idx)     = v0;
          *(float4*)(Cf + idx + 4) = v1;
        }
      }
    }
  } else {
    // EPI==2: fused RoPE + layout epilogue
    const int ncol0 = n0 + wn_ * 64;
    const int type = ncol0 >> 10;              // 0=q, 1=k, 2=v
    const int hd = (ncol0 & 1023) >> 6;        // head
    if (type == 2) {
      // V: vt[bh][d][LP] with d = ni*16+c; 4 consecutive l per (mi) -> bf16x4
#pragma unroll
      for (int mi = 0; mi < 4; ++mi) {
        const int rb = m0 + wm * 64 + mi * 16 + g * 4;
        const int b0 = rb / NL, b3 = (rb + 3) / NL;
        if (rb + 3 < M && b0 == b3) {
          const int l0_ = rb - b0 * NL;
          const size_t bhb = (size_t)(b0 * NHEADS + hd) * 64;
#pragma unroll
          for (int ni = 0; ni < 4; ++ni) {
            const int d = ni * 16 + c;
            bf16x4 v4;
#pragma unroll
            for (int j = 0; j < 4; ++j) v4[j] = (bf16)acc[mi][ni][j];
            *(bf16x4*)(vto + (bhb + d) * LP + l0_) = v4;
          }
        } else {
#pragma unroll
          for (int j = 0; j < 4; ++j) {
            const int row = rb + j;
            if (row < M) {
              const int b_ = row / NL, l = row - b_ * NL;
              const size_t bhb = (size_t)(b_ * NHEADS + hd) * 64;
#pragma unroll
              for (int ni = 0; ni < 4; ++ni)
                vto[(bhb + ni * 16 + c) * LP + l] = (bf16)acc[mi][ni][j];
            }
          }
        }
      }
    } else {
      bf16* dst = (type == 0) ? qro : kro;
      const float qs = (type == 0) ? QSCALE : 1.0f;
      // Per-wave private LDS transpose buffer: 64 x 72 bf16 (R20-proven).
      bf16* T = (wave < 2) ? (&Als[0][0] + wave * 4608)
                           : (&Bls[0][0] + (wave - 2) * 4608);
#pragma unroll
      for (int mi = 0; mi < 4; ++mi) {
#pragma unroll
        for (int j = 0; j < 4; ++j) {
          const int rowL = mi * 16 + g * 4 + j;
          const int rowG = m0 + wm * 64 + rowL;
          const int l = rowG - (rowG / NL) * NL;   // in [0, NL) even past M
          const float cf = cosT[l * 16 + c], sf = sinT[l * 16 + c];
          const float a0 = acc[mi][0][j], a1 = acc[mi][1][j];
          T[rowL * 72 + c]      = (bf16)((a0 * cf - a1 * sf) * qs);
          T[rowL * 72 + 16 + c] = (bf16)((a1 * cf + a0 * sf) * qs);
          T[rowL * 72 + 32 + c] = (bf16)(acc[mi][2][j] * qs);
          T[rowL * 72 + 48 + c] = (bf16)(acc[mi][3][j] * qs);
        }
      }
      // coalesced store: lanes 0..7 cover one full 128B row
#pragma unroll
      for (int i = 0; i < 8; ++i) {
        const int rowL = i * 8 + (lane >> 3);
        const int rowG = m0 + wm * 64 + rowL;
        if (rowG < M) {
          const int b_ = rowG / NL, l = rowG - b_ * NL;
          const size_t bse = ((size_t)(b_ * NHEADS + hd) * NL + l) * 64;
          const int ch = (lane & 7) * 8;
          *(bf16x8*)(dst + bse + ch) = *(const bf16x8*)&T[rowL * 72 + ch];
        }
      }
    }
  }
}

// ---------------- causal flash attention: dual-tile interleaved, no LDS ----
// One wave per slot; slot s<16 runs tiles {s, 31-s} interleaved in one kv loop;
// slot 16 runs tile 32 alone. P-repack lane exchange via v_permlane32_swap
// (VALU pipe). V clamp hoisted to a wave-uniform branch (only kv0=1024 clamps).
// No setprio (measured regression R9/R15). Base: R20 @409.0us.
__global__ __launch_bounds__(64) void k_attn(const bf16* __restrict__ qr,
                                             const bf16* __restrict__ kr,
                                             const bf16* __restrict__ vt,
                                             bf16* __restrict__ oa) {
  const int bid = blockIdx.x;                    // grid = 4352 = 8 * 544
  const int lbid = (bid & 7) * (NBH * NSLOT / 8) + (bid >> 3);  // XCD-grouped
  const int slot = lbid % NSLOT, bh = lbid / NSLOT;
  const int b = bh >> 4, h = bh & 15;
  const int lane = threadIdx.x;
  const int ql = lane & 31;                      // q-col / kv-row / d-col index
  const int hh = lane >> 5;                      // half (k-chunk selector)
  const bf16* qb = qr + (size_t)bh * NL * 64;
  const bf16* kb = kr + (size_t)bh * NL * 64;
  const bf16* vb = vt + (size_t)bh * 64 * LP;

  const int tA = (slot < 16) ? slot : -1;
  const int tB = (slot < 16) ? 31 - slot : 32;
  const bool hasA = (tA >= 0);

  const int q0A = tA * 32, q0B = tB * 32;
  const int qabsA = q0A + ql, qabsB = q0B + ql;

  bf16x8 bQA[4], bQB[4];
  {
    const int qrB = (q0B + ql < NL) ? q0B + ql : NL - 1;
#pragma unroll
    for (int kc = 0; kc < 4; ++kc)
      bQB[kc] = *(const bf16x8*)(qb + (size_t)qrB * 64 + kc * 16 + hh * 8);
    const int qrA = hasA ? q0A + ql : 0;
#pragma unroll
    for (int kc = 0; kc < 4; ++kc)
      bQA[kc] = *(const bf16x8*)(qb + (size_t)qrA * 64 + kc * 16 + hh * 8);
  }

  f32x16 odA0 = zero16(), odA1 = zero16(), odB0 = zero16(), odB1 = zero16();
  float lsA = 0.f, lsB = 0.f;

  const int ntA = hasA ? ((q0A + 31) / 64 + 1) : 0;
  const int qmaxB = (q0B + 31 < NL - 1) ? q0B + 31 : NL - 1;
  const int ntB = qmaxB / 64 + 1;               // ntA <= ntB always

  bf16x8 aK[2][4];
  auto loadK = [&](int kv0) {
#pragma unroll
    for (int blk = 0; blk < 2; ++blk) {
      int r = kv0 + blk * 32 + ql; if (r >= NL) r = NL - 1;
      const bf16* kp = kb + (size_t)r * 64 + hh * 8;
#pragma unroll
      for (int kc = 0; kc < 4; ++kc)
        aK[blk][kc] = *(const bf16x8*)(kp + kc * 16);
    }
  };
  loadK(0);

  auto smrepack = [&](const f32x16& s0, const f32x16& s1, int kv0, int q0,
                      int qabs, float& ls, bf16x8 (&pa)[4]) {
    const bool needmask = (kv0 + 63 > q0);
#pragma unroll
    for (int blk = 0; blk < 2; ++blk) {
      const f32x16& s = blk ? s1 : s0;
      float p[16];
#pragma unroll
      for (int r = 0; r < 16; ++r) {
        float v = s[r];
        if (needmask) {
          const int kvabs = kv0 + blk * 32 + (r & 3) + 8 * (r >> 2) + 4 * hh;
          if (kvabs > qabs) v = -1e30f;
        }
        p[r] = fexp2(v);
      }
      ls += (((p[0]+p[1])+(p[2]+p[3])) + ((p[4]+p[5])+(p[6]+p[7])))
          + (((p[8]+p[9])+(p[10]+p[11])) + ((p[12]+p[13])+(p[14]+p[15])));
      uint32_t w[8];
#pragma unroll
      for (int a = 0; a < 8; ++a) w[a] = cvtpk(p[2*a], p[2*a+1]);
      // VALU-pipe exchange (replaces 4 DS shuffles):
      uint32_t a0 = w[0], b0 = w[2]; plswap(a0, b0);
      uint32_t a1 = w[1], b1 = w[3]; plswap(a1, b1);
      uint32_t a2 = w[4], b2 = w[6]; plswap(a2, b2);
      uint32_t a3 = w[5], b3 = w[7]; plswap(a3, b3);
      u32x4 w0_, w1_;
      w0_[0] = a0; w0_[1] = a1; w0_[2] = b0; w0_[3] = b1;
      w1_[0] = a2; w1_[1] = a3; w1_[2] = b2; w1_[3] = b3;
      pa[2*blk]     = __builtin_bit_cast(bf16x8, w0_);
      pa[2*blk + 1] = __builtin_bit_cast(bf16x8, w1_);
    }
  };

  for (int tk = 0; tk < ntB; ++tk) {
    const int kv0 = tk * 64;
    const bool actA = hasA && (tk < ntA);

    bf16x8 vf[2][4];
    if (kv0 <= 992) {                         // uniform fast path (no clamp)
#pragma unroll
      for (int dblk = 0; dblk < 2; ++dblk) {
        const bf16* vp = vb + (size_t)(dblk * 32 + ql) * LP + kv0 + hh * 8;
#pragma unroll
        for (int kc = 0; kc < 4; ++kc)
          vf[dblk][kc] = *(const bf16x8*)(vp + kc * 16);
      }
    } else {
#pragma unroll
      for (int dblk = 0; dblk < 2; ++dblk) {
        const bf16* vp = vb + (size_t)(dblk * 32 + ql) * LP;
#pragma unroll
        for (int kc = 0; kc < 4; ++kc) {
          int col = kv0 + kc * 16 + hh * 8;
          if (col > LP - 8) col = LP - 8;     // final-tile clamp (P=0 there)
          vf[dblk][kc] = *(const bf16x8*)(vp + col);
        }
      }
    }

    bf16x8 paA[4];
    if (actA) {
      f32x16 s0 = zero16(), s1 = zero16();
#pragma unroll
      for (int kc = 0; kc < 4; ++kc)
        s0 = __builtin_amdgcn_mfma_f32_32x32x16_bf16(aK[0][kc], bQA[kc], s0, 0, 0, 0);
#pragma unroll
      for (int kc = 0; kc < 4; ++kc)
        s1 = __builtin_amdgcn_mfma_f32_32x32x16_bf16(aK[1][kc], bQA[kc], s1, 0, 0, 0);
      smrepack(s0, s1, kv0, q0A, qabsA, lsA, paA);
    }

    f32x16 sB0 = zero16(), sB1 = zero16();
#pragma unroll
    for (int kc = 0; kc < 4; ++kc)
      sB0 = __builtin_amdgcn_mfma_f32_32x32x16_bf16(aK[0][kc], bQB[kc], sB0, 0, 0, 0);
#pragma unroll
    for (int kc = 0; kc < 4; ++kc)
      sB1 = __builtin_amdgcn_mfma_f32_32x32x16_bf16(aK[1][kc], bQB[kc], sB1, 0, 0, 0);

    if (tk + 1 < ntB) loadK(kv0 + 64);

    if (actA) {
#pragma unroll
      for (int kc = 0; kc < 4; ++kc) {
        odA0 = __builtin_amdgcn_mfma_f32_32x32x16_bf16(paA[kc], vf[0][kc], odA0, 0, 0, 0);
        odA1 = __builtin_amdgcn_mfma_f32_32x32x16_bf16(paA[kc], vf[1][kc], odA1, 0, 0, 0);
      }
    }

    bf16x8 paB[4];
    smrepack(sB0, sB1, kv0, q0B, qabsB, lsB, paB);

#pragma unroll
    for (int kc = 0; kc < 4; ++kc) {
      odB0 = __builtin_amdgcn_mfma_f32_32x32x16_bf16(paB[kc], vf[0][kc], odB0, 0, 0, 0);
      odB1 = __builtin_amdgcn_mfma_f32_32x32x16_bf16(paB[kc], vf[1][kc], odB1, 0, 0, 0);
    }
  }

  auto fin = [&](int q0, float ls, const f32x16& od0, const f32x16& od1) {
    const float tot = ls + __shfl_xor(ls, 32);
    const float invOwn = 1.0f / tot;
#pragma unroll
    for (int r = 0; r < 16; ++r) {
      const int qrl = (r & 3) + 8 * (r >> 2) + 4 * hh;   // local q row of reg r
      const float inv = __shfl(invOwn, qrl);
      const int row = q0 + qrl;
      if (row < NL) {
        const size_t ob = (size_t)(b * NL + row) * NDIM + h * 64;
        oa[ob + ql]      = (bf16)(od0[r] * inv);
        oa[ob + 32 + ql] = (bf16)(od1[r] * inv);
      }
    }
  };
  if (hasA) fin(q0A, lsA, odA0, odA1);
  fin(q0B, lsB, odB0, odB1);
}

extern "C" void kernel_launch(void* const* d_in, const int* in_sizes, int n_in,
                              void* d_out, int out_size, void* d_ws, size_t ws_size,
                              hipStream_t stream) {
  const float* x     = (const float*)d_in[0];
  const float* cond  = (const float*)d_in[1];
  const float* wnorm = (const float*)d_in[2];
  const float* wqkv  = (const float*)d_in[3];
  const float* wout  = (const float*)d_in[4];
  const float* cosT  = (const float*)d_in[5];
  const float* sinT  = (const float*)d_in[6];
  float* out = (float*)d_out;
  char* ws = (char*)d_ws;

  float* s_scl = (float*)(ws);                    //    65,536 B
  bf16*  s_wq  = (bf16*)(ws + 65536);             // 6,291,456 B
  bf16*  s_wo  = (bf16*)(ws + 6356992);           // 2,097,152 B
  bf16*  s_xn  = (bf16*)(ws + 8454144);           // 33,587,200 B (reused as attn out)
  bf16*  s_qr  = (bf16*)(ws + 142802944);         // 33,587,200 B
  bf16*  s_kr  = (bf16*)(ws + 176390144);         // 33,587,200 B
  bf16*  s_vt  = (bf16*)(ws + 209977344);         // 34,603,008 B -> end 244,580,352 B

  k_prep<<<4112, 256, 0, stream>>>(wqkv, wout, cond, wnorm, s_wq, s_wo, s_scl);
  k_rmsnorm<<<NML, 256, 0, stream>>>(x, s_scl, s_xn);
  k_gemm<2><<<3096, 256, 0, stream>>>(s_xn, s_wq, NML, 3 * NDIM, NDIM,
                                      nullptr, nullptr, s_qr, s_kr, s_vt,
                                      cosT, sinT);
  k_attn<<<NBH * NSLOT, 64, 0, stream>>>(s_qr, s_kr, s_vt, s_xn);
  k_gemm<1><<<1032, 256, 0, stream>>>(s_xn, s_wo, NML, NDIM, NDIM,
                                      out, x, nullptr, nullptr, nullptr,
                                      nullptr, nullptr);
}